// Round 1
// baseline (356.840 us; speedup 1.0000x reference)
//
#include <hip/hip_runtime.h>

// Problem constants (fixed by setup_inputs): B=32, C=256, H=W=56
#define C_CH 256
#define B_N  32
#define HW   3136   // 56*56
#define HW4  784    // HW/4 (float4 granules per plane) = 3*256 + 16

typedef float v4f __attribute__((ext_vector_type(4)));

// ---------------------------------------------------------------------------
// Kernel 1: per-channel source-selection tables (unchanged — verified absmax=0).
// sel[0..255]   : feature1 -> source channel in x2, or -1 (keep x1[c])
// sel[256..511] : feature2 -> source channel in x1, or -1 (keep x2[c])
// ---------------------------------------------------------------------------
__global__ void setup_sel_kernel(const float* __restrict__ w1,
                                 const float* __restrict__ w2,
                                 const float* __restrict__ thr_p,
                                 int* __restrict__ sel)
{
    __shared__ float a1[C_CH], a2[C_CH];
    __shared__ int order1[C_CH], order2[C_CH];
    __shared__ int cum1[C_CH], cum2[C_CH];

    const int i = threadIdx.x;
    a1[i] = fabsf(w1[i]);
    a2[i] = fabsf(w2[i]);
    __syncthreads();

    const float v1 = a1[i], v2 = a2[i];
    int r1 = 0, r2 = 0;
    #pragma unroll 16
    for (int j = 0; j < C_CH; ++j) {
        const float b1 = a1[j], b2 = a2[j];
        r1 += (b1 > v1) || (b1 == v1 && j < i);
        r2 += (b2 > v2) || (b2 == v2 && j < i);
    }
    order1[r1] = i;   // order1[k] = channel with k-th largest |w1|
    order2[r2] = i;

    const float thr = thr_p[0];
    const int below1 = (v1 < thr) ? 1 : 0;
    const int below2 = (v2 < thr) ? 1 : 0;
    cum1[i] = below1;
    cum2[i] = below2;
    __syncthreads();

    // Inclusive parallel scan over 256 elements (8 steps).
    #pragma unroll
    for (int off = 1; off < C_CH; off <<= 1) {
        const int t1 = (i >= off) ? cum1[i - off] : 0;
        const int t2 = (i >= off) ? cum2[i - off] : 0;
        __syncthreads();
        cum1[i] += t1;
        cum2[i] += t2;
        __syncthreads();
    }

    int rk1 = cum1[i] - 1; if (rk1 < 0) rk1 = 0;   // clip(cumsum-1, 0)
    int rk2 = cum2[i] - 1; if (rk2 < 0) rk2 = 0;

    sel[i]        = below1 ? order2[rk1] : -1;
    sel[C_CH + i] = below2 ? order1[rk2] : -1;
}

// ---------------------------------------------------------------------------
// Kernel 2: plane copy/gather, v2.
//   - 2048 blocks x 256 threads = 8 blocks/CU on 256 CUs -> full residency
//     (32 waves/CU), 8 planes per block.
//   - b-major plane order: plane P = b*512 + out*256 + c. Both reads of a
//     duplicated source plane (replace-source for one feature, keep-source
//     for the other) now occur within the same batch window.
//   - CACHED loads (input total 205.5 MB < 256 MB L3; ~38% of planes are
//     read twice -> second read should be an L3 hit). NT stores only
//     (outputs are write-once, keep them out of the cache).
//   - sel value for the next plane is prefetched to break the
//     sel-load -> address -> data-load dependency chain.
// ---------------------------------------------------------------------------
__global__ __launch_bounds__(256)
void gather_planes_kernel(const v4f* __restrict__ x1,
                          const v4f* __restrict__ x2,
                          const int* __restrict__ sel,
                          v4f*       __restrict__ out)
{
    const unsigned P0  = blockIdx.x * 8u;       // first plane (b-major order)
    const unsigned b   = P0 >> 9;               // batch index
    const int      oid = (P0 >> 8) & 1;         // 0 -> feature1, 1 -> feature2
    const unsigned c0  = P0 & 255;              // first channel of this run

    const v4f* __restrict__ primary = oid ? x2 : x1;
    const v4f* __restrict__ other   = oid ? x1 : x2;

    const int t = threadIdx.x;
    const size_t bc0 = (size_t)b * C_CH + c0;
    const v4f* __restrict__ prim = primary + bc0 * HW4 + t;
    v4f* __restrict__ dst        = out + ((size_t)oid * (B_N * C_CH) + bc0) * HW4 + t;
    const int selbase = oid * C_CH + c0;

    int s_next = sel[selbase];                  // prefetch first sel

    #pragma unroll 2
    for (int i = 0; i < 8; ++i) {
        const int s = s_next;
        if (i < 7) s_next = sel[selbase + i + 1];   // prefetch next (L1 hit)

        const v4f* __restrict__ src = (s >= 0)
            ? other + ((size_t)b * C_CH + (size_t)s) * HW4 + t
            : prim + (size_t)i * HW4;
        v4f* __restrict__ d = dst + (size_t)i * HW4;

        const v4f r0 = src[0];
        const v4f r1 = src[256];
        const v4f r2 = src[512];
        __builtin_nontemporal_store(r0, d);
        __builtin_nontemporal_store(r1, d + 256);
        __builtin_nontemporal_store(r2, d + 512);
        if (t < 16) {
            const v4f r3 = src[768];
            __builtin_nontemporal_store(r3, d + 768);
        }
    }
}

extern "C" void kernel_launch(void* const* d_in, const int* in_sizes, int n_in,
                              void* d_out, int out_size, void* d_ws, size_t ws_size,
                              hipStream_t stream)
{
    const float* x1  = (const float*)d_in[0];
    const float* x2  = (const float*)d_in[1];
    const float* w1  = (const float*)d_in[2];
    const float* w2  = (const float*)d_in[3];
    const float* thr = (const float*)d_in[4];

    int* sel = (int*)d_ws;   // 512 ints = 2 KiB of scratch

    setup_sel_kernel<<<1, C_CH, 0, stream>>>(w1, w2, thr, sel);

    gather_planes_kernel<<<(2 * B_N * C_CH) / 8, 256, 0, stream>>>(
        (const v4f*)x1, (const v4f*)x2, sel, (v4f*)d_out);
}

// Round 3
// 354.564 us; speedup vs baseline: 1.0064x; 1.0064x over previous
//
#include <hip/hip_runtime.h>

// Problem constants (fixed by setup_inputs): B=32, C=256, H=W=56
#define C_CH 256
#define B_N  32
#define HW   3136   // 56*56
#define HW4  784    // HW/4 (float4 granules per plane) = 3*256 + 16

typedef float v4f __attribute__((ext_vector_type(4)));

// ---------------------------------------------------------------------------
// Kernel 1: per-channel source-selection tables (unchanged — verified absmax=0
// across two benches).
// sel[0..255]   : feature1 -> source channel in x2, or -1 (keep x1[c])
// sel[256..511] : feature2 -> source channel in x1, or -1 (keep x2[c])
// ---------------------------------------------------------------------------
__global__ void setup_sel_kernel(const float* __restrict__ w1,
                                 const float* __restrict__ w2,
                                 const float* __restrict__ thr_p,
                                 int* __restrict__ sel)
{
    __shared__ float a1[C_CH], a2[C_CH];
    __shared__ int order1[C_CH], order2[C_CH];
    __shared__ int cum1[C_CH], cum2[C_CH];

    const int i = threadIdx.x;
    a1[i] = fabsf(w1[i]);
    a2[i] = fabsf(w2[i]);
    __syncthreads();

    const float v1 = a1[i], v2 = a2[i];
    int r1 = 0, r2 = 0;
    #pragma unroll 16
    for (int j = 0; j < C_CH; ++j) {
        const float b1 = a1[j], b2 = a2[j];
        r1 += (b1 > v1) || (b1 == v1 && j < i);
        r2 += (b2 > v2) || (b2 == v2 && j < i);
    }
    order1[r1] = i;   // order1[k] = channel with k-th largest |w1|
    order2[r2] = i;

    const float thr = thr_p[0];
    const int below1 = (v1 < thr) ? 1 : 0;
    const int below2 = (v2 < thr) ? 1 : 0;
    cum1[i] = below1;
    cum2[i] = below2;
    __syncthreads();

    // Inclusive parallel scan over 256 elements (8 steps).
    #pragma unroll
    for (int off = 1; off < C_CH; off <<= 1) {
        const int t1 = (i >= off) ? cum1[i - off] : 0;
        const int t2 = (i >= off) ? cum2[i - off] : 0;
        __syncthreads();
        cum1[i] += t1;
        cum2[i] += t2;
        __syncthreads();
    }

    int rk1 = cum1[i] - 1; if (rk1 < 0) rk1 = 0;   // clip(cumsum-1, 0)
    int rk2 = cum2[i] - 1; if (rk2 < 0) rk2 = 0;

    sel[i]        = below1 ? order2[rk1] : -1;
    sel[C_CH + i] = below2 ? order1[rk2] : -1;
}

// ---------------------------------------------------------------------------
// Kernel 2: plane copy/gather — round-0 structure (best measured: 342-345 us),
// single targeted delta: CACHED loads (was nontemporal), NT stores kept.
// Rationale: ~196/512 planes per batch are read twice (replacement sources
// are exactly the other feature's keep-planes). Unique read set ~127 MB fits
// the 256 MB L3 and persists across graph replays; NT loads were forcing
// every duplicate (and every replay) back to HBM.
// One block per (output, b, c) plane: grid = 16384 blocks x 256 threads,
// block-uniform source selection, fully coalesced float4 traffic.
// 784 granules = 3 full rounds + 16-lane tail; loads issued before stores.
// ---------------------------------------------------------------------------
__global__ __launch_bounds__(256)
void gather_planes_kernel(const v4f* __restrict__ x1,
                          const v4f* __restrict__ x2,
                          const int* __restrict__ sel,
                          v4f*       __restrict__ out)
{
    const unsigned blk = blockIdx.x;
    const int out_id = blk >> 13;        // 0 -> feature1, 1 -> feature2 (8192 = B*C)
    const int bc     = blk & 8191;       // b*C + c
    const int c      = bc & 255;
    const size_t b   = (size_t)(bc >> 8);

    const v4f* primary = out_id ? x2 : x1;
    const v4f* other   = out_id ? x1 : x2;

    const int s = sel[out_id * C_CH + c];

    const v4f* src = (s >= 0)
        ? other + (b * C_CH + (size_t)s) * HW4
        : primary + (size_t)bc * HW4;

    v4f* dst = out + ((size_t)out_id * (B_N * C_CH) + (size_t)bc) * HW4;

    const int t = threadIdx.x;
    const v4f r0 = src[t];
    const v4f r1 = src[t + 256];
    const v4f r2 = src[t + 512];
    __builtin_nontemporal_store(r0, dst + t);
    __builtin_nontemporal_store(r1, dst + t + 256);
    __builtin_nontemporal_store(r2, dst + t + 512);
    if (t < 16) {
        const v4f r3 = src[t + 768];
        __builtin_nontemporal_store(r3, dst + t + 768);
    }
}

extern "C" void kernel_launch(void* const* d_in, const int* in_sizes, int n_in,
                              void* d_out, int out_size, void* d_ws, size_t ws_size,
                              hipStream_t stream)
{
    const float* x1  = (const float*)d_in[0];
    const float* x2  = (const float*)d_in[1];
    const float* w1  = (const float*)d_in[2];
    const float* w2  = (const float*)d_in[3];
    const float* thr = (const float*)d_in[4];

    int* sel = (int*)d_ws;   // 512 ints = 2 KiB of scratch

    setup_sel_kernel<<<1, C_CH, 0, stream>>>(w1, w2, thr, sel);

    gather_planes_kernel<<<2 * B_N * C_CH, 256, 0, stream>>>(
        (const v4f*)x1, (const v4f*)x2, sel, (v4f*)d_out);
}

// Round 4
// 344.133 us; speedup vs baseline: 1.0369x; 1.0303x over previous
//
#include <hip/hip_runtime.h>

// Problem constants (fixed by setup_inputs): B=32, C=256, H=W=56
#define C_CH 256
#define B_N  32
#define HW   3136   // 56*56
#define HW4  784    // HW/4 (float4 granules per plane) = 3*256 + 16

typedef float v4f __attribute__((ext_vector_type(4)));

// ---------------------------------------------------------------------------
// Kernel 1: per-channel source-selection tables.
// sel[0..255]   : feature1 -> source channel in x2, or -1 (keep x1[c])
// sel[256..511] : feature2 -> source channel in x1, or -1 (keep x2[c])
// rank = #{j: a[j]>a[i]} + #{j<i: a[j]==a[i]}  (stable descending argsort).
// ---------------------------------------------------------------------------
__global__ void setup_sel_kernel(const float* __restrict__ w1,
                                 const float* __restrict__ w2,
                                 const float* __restrict__ thr_p,
                                 int* __restrict__ sel)
{
    __shared__ float a1[C_CH], a2[C_CH];
    __shared__ int order1[C_CH], order2[C_CH];
    __shared__ int cum1[C_CH], cum2[C_CH];

    const int i = threadIdx.x;
    a1[i] = fabsf(w1[i]);
    a2[i] = fabsf(w2[i]);
    __syncthreads();

    const float v1 = a1[i], v2 = a2[i];
    int r1 = 0, r2 = 0;
    #pragma unroll 16
    for (int j = 0; j < C_CH; ++j) {
        const float b1 = a1[j], b2 = a2[j];
        r1 += (b1 > v1) || (b1 == v1 && j < i);
        r2 += (b2 > v2) || (b2 == v2 && j < i);
    }
    order1[r1] = i;   // order1[k] = channel with k-th largest |w1|
    order2[r2] = i;

    const float thr = thr_p[0];
    const int below1 = (v1 < thr) ? 1 : 0;
    const int below2 = (v2 < thr) ? 1 : 0;
    cum1[i] = below1;
    cum2[i] = below2;
    __syncthreads();

    // Inclusive parallel scan over 256 elements (8 steps).
    #pragma unroll
    for (int off = 1; off < C_CH; off <<= 1) {
        const int t1 = (i >= off) ? cum1[i - off] : 0;
        const int t2 = (i >= off) ? cum2[i - off] : 0;
        __syncthreads();
        cum1[i] += t1;
        cum2[i] += t2;
        __syncthreads();
    }

    int rk1 = cum1[i] - 1; if (rk1 < 0) rk1 = 0;   // clip(cumsum-1, 0)
    int rk2 = cum2[i] - 1; if (rk2 < 0) rk2 = 0;

    sel[i]        = below1 ? order2[rk1] : -1;
    sel[C_CH + i] = below2 ? order1[rk2] : -1;
}

// ---------------------------------------------------------------------------
// Kernel 2: plane copy/gather — best-measured configuration (342.6 / 344.6 us).
// One block per (output, b, c) plane: grid = 16384 blocks x 256 threads,
// block-uniform source selection, fully coalesced float4 traffic,
// NONTEMPORAL loads AND stores.
// Measured A/B (round 0 vs round 3, same structure): NT loads beat cached
// loads by ~10 us. Interpretation: Infinity Cache is memory-side and serves
// the ~78 MB of duplicate plane reads regardless of the NT hint; cached
// loads only added L1/L2 pollution against the NT write stream.
// 784 granules = 3 full rounds + 16-lane tail; loads issued before stores.
// ---------------------------------------------------------------------------
__global__ __launch_bounds__(256)
void gather_planes_kernel(const v4f* __restrict__ x1,
                          const v4f* __restrict__ x2,
                          const int* __restrict__ sel,
                          v4f*       __restrict__ out)
{
    const unsigned blk = blockIdx.x;
    const int out_id = blk >> 13;        // 0 -> feature1, 1 -> feature2 (8192 = B*C)
    const int bc     = blk & 8191;       // b*C + c
    const int c      = bc & 255;
    const size_t b   = (size_t)(bc >> 8);

    const v4f* primary = out_id ? x2 : x1;
    const v4f* other   = out_id ? x1 : x2;

    const int s = sel[out_id * C_CH + c];

    const v4f* src = (s >= 0)
        ? other + (b * C_CH + (size_t)s) * HW4
        : primary + (size_t)bc * HW4;

    v4f* dst = out + ((size_t)out_id * (B_N * C_CH) + (size_t)bc) * HW4;

    const int t = threadIdx.x;
    const v4f r0 = __builtin_nontemporal_load(src + t);
    const v4f r1 = __builtin_nontemporal_load(src + t + 256);
    const v4f r2 = __builtin_nontemporal_load(src + t + 512);
    __builtin_nontemporal_store(r0, dst + t);
    __builtin_nontemporal_store(r1, dst + t + 256);
    __builtin_nontemporal_store(r2, dst + t + 512);
    if (t < 16) {
        const v4f r3 = __builtin_nontemporal_load(src + t + 768);
        __builtin_nontemporal_store(r3, dst + t + 768);
    }
}

extern "C" void kernel_launch(void* const* d_in, const int* in_sizes, int n_in,
                              void* d_out, int out_size, void* d_ws, size_t ws_size,
                              hipStream_t stream)
{
    const float* x1  = (const float*)d_in[0];
    const float* x2  = (const float*)d_in[1];
    const float* w1  = (const float*)d_in[2];
    const float* w2  = (const float*)d_in[3];
    const float* thr = (const float*)d_in[4];

    int* sel = (int*)d_ws;   // 512 ints = 2 KiB of scratch

    setup_sel_kernel<<<1, C_CH, 0, stream>>>(w1, w2, thr, sel);

    gather_planes_kernel<<<2 * B_N * C_CH, 256, 0, stream>>>(
        (const v4f*)x1, (const v4f*)x2, sel, (v4f*)d_out);
}

// Round 5
// 339.864 us; speedup vs baseline: 1.0499x; 1.0126x over previous
//
#include <hip/hip_runtime.h>

// Problem constants (fixed by setup_inputs): B=32, C=256, H=W=56
#define C_CH 256
#define B_N  32
#define HW   3136   // 56*56
#define HW4  784    // HW/4 (float4 granules per plane) = 512 + 272

typedef float v4f __attribute__((ext_vector_type(4)));

// ---------------------------------------------------------------------------
// Kernel 1: per-channel source-selection tables (verified absmax=0, ~3-5 us).
// sel[0..255]   : feature1 -> source channel in x2, or -1 (keep x1[c])
// sel[256..511] : feature2 -> source channel in x1, or -1 (keep x2[c])
// rank = #{j: a[j]>a[i]} + #{j<i: a[j]==a[i]}  (stable descending argsort).
// ---------------------------------------------------------------------------
__global__ void setup_sel_kernel(const float* __restrict__ w1,
                                 const float* __restrict__ w2,
                                 const float* __restrict__ thr_p,
                                 int* __restrict__ sel)
{
    __shared__ float a1[C_CH], a2[C_CH];
    __shared__ int order1[C_CH], order2[C_CH];
    __shared__ int cum1[C_CH], cum2[C_CH];

    const int i = threadIdx.x;
    a1[i] = fabsf(w1[i]);
    a2[i] = fabsf(w2[i]);
    __syncthreads();

    const float v1 = a1[i], v2 = a2[i];
    int r1 = 0, r2 = 0;
    #pragma unroll 16
    for (int j = 0; j < C_CH; ++j) {
        const float b1 = a1[j], b2 = a2[j];
        r1 += (b1 > v1) || (b1 == v1 && j < i);
        r2 += (b2 > v2) || (b2 == v2 && j < i);
    }
    order1[r1] = i;   // order1[k] = channel with k-th largest |w1|
    order2[r2] = i;

    const float thr = thr_p[0];
    const int below1 = (v1 < thr) ? 1 : 0;
    const int below2 = (v2 < thr) ? 1 : 0;
    cum1[i] = below1;
    cum2[i] = below2;
    __syncthreads();

    // Inclusive parallel scan over 256 elements (8 steps).
    #pragma unroll
    for (int off = 1; off < C_CH; off <<= 1) {
        const int t1 = (i >= off) ? cum1[i - off] : 0;
        const int t2 = (i >= off) ? cum2[i - off] : 0;
        __syncthreads();
        cum1[i] += t1;
        cum2[i] += t2;
        __syncthreads();
    }

    int rk1 = cum1[i] - 1; if (rk1 < 0) rk1 = 0;   // clip(cumsum-1, 0)
    int rk2 = cum2[i] - 1; if (rk2 < 0) rk2 = 0;

    sel[i]        = below1 ? order2[rk1] : -1;
    sel[C_CH + i] = below2 ? order1[rk2] : -1;
}

// ---------------------------------------------------------------------------
// Kernel 2: plane copy/gather. One block per (output, b, c) plane.
// Delta vs best-measured 342.6/344.1 config (the ONLY change this round):
//   512 threads/block instead of 256 -> 2 load/store rounds per block
//   (t, t+512<784) instead of 3.06, and ALL loads (incl. the 272-granule
//   tail) are issued before any store, so a block's full read burst is in
//   flight at once. Tests whether the gather is block-turnover/latency
//   limited rather than BW-limited.
// NT loads AND stores (measured: cached loads cost +11 us — L3 is
// memory-side and serves duplicate plane reads regardless; caching only
// pollutes L1/L2 against the NT write stream).
// ---------------------------------------------------------------------------
__global__ __launch_bounds__(512)
void gather_planes_kernel(const v4f* __restrict__ x1,
                          const v4f* __restrict__ x2,
                          const int* __restrict__ sel,
                          v4f*       __restrict__ out)
{
    const unsigned blk = blockIdx.x;
    const int out_id = blk >> 13;        // 0 -> feature1, 1 -> feature2 (8192 = B*C)
    const int bc     = blk & 8191;       // b*C + c
    const int c      = bc & 255;
    const size_t b   = (size_t)(bc >> 8);

    const v4f* primary = out_id ? x2 : x1;
    const v4f* other   = out_id ? x1 : x2;

    const int s = sel[out_id * C_CH + c];

    const v4f* src = (s >= 0)
        ? other + (b * C_CH + (size_t)s) * HW4
        : primary + (size_t)bc * HW4;

    v4f* dst = out + ((size_t)out_id * (B_N * C_CH) + (size_t)bc) * HW4;

    const int t = threadIdx.x;
    const bool tail = (t < HW4 - 512);   // t < 272
    const v4f r0 = __builtin_nontemporal_load(src + t);
    v4f r1;
    if (tail) r1 = __builtin_nontemporal_load(src + t + 512);
    __builtin_nontemporal_store(r0, dst + t);
    if (tail) __builtin_nontemporal_store(r1, dst + t + 512);
}

extern "C" void kernel_launch(void* const* d_in, const int* in_sizes, int n_in,
                              void* d_out, int out_size, void* d_ws, size_t ws_size,
                              hipStream_t stream)
{
    const float* x1  = (const float*)d_in[0];
    const float* x2  = (const float*)d_in[1];
    const float* w1  = (const float*)d_in[2];
    const float* w2  = (const float*)d_in[3];
    const float* thr = (const float*)d_in[4];

    int* sel = (int*)d_ws;   // 512 ints = 2 KiB of scratch

    setup_sel_kernel<<<1, C_CH, 0, stream>>>(w1, w2, thr, sel);

    gather_planes_kernel<<<2 * B_N * C_CH, 512, 0, stream>>>(
        (const v4f*)x1, (const v4f*)x2, sel, (v4f*)d_out);
}

// Round 6
// 338.798 us; speedup vs baseline: 1.0533x; 1.0031x over previous
//
#include <hip/hip_runtime.h>

// Problem constants (fixed by setup_inputs): B=32, C=256, H=W=56
#define C_CH 256
#define B_N  32
#define HW   3136   // 56*56
#define HW4  784    // HW/4 (float4 granules per plane)

typedef float v4f __attribute__((ext_vector_type(4)));

// ---------------------------------------------------------------------------
// Kernel 1: per-channel source-selection tables (verified absmax=0, ~3-5 us).
// sel[0..255]   : feature1 -> source channel in x2, or -1 (keep x1[c])
// sel[256..511] : feature2 -> source channel in x1, or -1 (keep x2[c])
// rank = #{j: a[j]>a[i]} + #{j<i: a[j]==a[i]}  (stable descending argsort).
// ---------------------------------------------------------------------------
__global__ void setup_sel_kernel(const float* __restrict__ w1,
                                 const float* __restrict__ w2,
                                 const float* __restrict__ thr_p,
                                 int* __restrict__ sel)
{
    __shared__ float a1[C_CH], a2[C_CH];
    __shared__ int order1[C_CH], order2[C_CH];
    __shared__ int cum1[C_CH], cum2[C_CH];

    const int i = threadIdx.x;
    a1[i] = fabsf(w1[i]);
    a2[i] = fabsf(w2[i]);
    __syncthreads();

    const float v1 = a1[i], v2 = a2[i];
    int r1 = 0, r2 = 0;
    #pragma unroll 16
    for (int j = 0; j < C_CH; ++j) {
        const float b1 = a1[j], b2 = a2[j];
        r1 += (b1 > v1) || (b1 == v1 && j < i);
        r2 += (b2 > v2) || (b2 == v2 && j < i);
    }
    order1[r1] = i;   // order1[k] = channel with k-th largest |w1|
    order2[r2] = i;

    const float thr = thr_p[0];
    const int below1 = (v1 < thr) ? 1 : 0;
    const int below2 = (v2 < thr) ? 1 : 0;
    cum1[i] = below1;
    cum2[i] = below2;
    __syncthreads();

    // Inclusive parallel scan over 256 elements (8 steps).
    #pragma unroll
    for (int off = 1; off < C_CH; off <<= 1) {
        const int t1 = (i >= off) ? cum1[i - off] : 0;
        const int t2 = (i >= off) ? cum2[i - off] : 0;
        __syncthreads();
        cum1[i] += t1;
        cum2[i] += t2;
        __syncthreads();
    }

    int rk1 = cum1[i] - 1; if (rk1 < 0) rk1 = 0;   // clip(cumsum-1, 0)
    int rk2 = cum2[i] - 1; if (rk2 < 0) rk2 = 0;

    sel[i]        = below1 ? order2[rk1] : -1;
    sel[C_CH + i] = below2 ? order1[rk2] : -1;
}

// ---------------------------------------------------------------------------
// Kernel 2: plane copy/gather. One block per (output, b, c) plane.
// Round-to-round ladder (same structure, measured):
//   256 thr / 3.06 rounds : 342.6 / 344.6 / 344.1 us
//   512 thr / 2 rounds    : 339.9 us   (fewer serial dependent rounds helps)
//   832 thr / 1 round     : this round — logical endpoint: one NT load + one
//                           NT store per active thread, zero serial rounds,
//                           only the last wave carries the t<784 guard.
// NT loads AND stores (measured: cached loads cost +11 us — L3 is
// memory-side and serves duplicate plane reads regardless; caching only
// pollutes L1/L2 against the NT write stream).
// ---------------------------------------------------------------------------
__global__ __launch_bounds__(832)
void gather_planes_kernel(const v4f* __restrict__ x1,
                          const v4f* __restrict__ x2,
                          const int* __restrict__ sel,
                          v4f*       __restrict__ out)
{
    const unsigned blk = blockIdx.x;
    const int out_id = blk >> 13;        // 0 -> feature1, 1 -> feature2 (8192 = B*C)
    const int bc     = blk & 8191;       // b*C + c
    const int c      = bc & 255;
    const size_t b   = (size_t)(bc >> 8);

    const v4f* primary = out_id ? x2 : x1;
    const v4f* other   = out_id ? x1 : x2;

    const int s = sel[out_id * C_CH + c];

    const v4f* src = (s >= 0)
        ? other + (b * C_CH + (size_t)s) * HW4
        : primary + (size_t)bc * HW4;

    v4f* dst = out + ((size_t)out_id * (B_N * C_CH) + (size_t)bc) * HW4;

    const int t = threadIdx.x;
    if (t < HW4) {
        const v4f r0 = __builtin_nontemporal_load(src + t);
        __builtin_nontemporal_store(r0, dst + t);
    }
}

extern "C" void kernel_launch(void* const* d_in, const int* in_sizes, int n_in,
                              void* d_out, int out_size, void* d_ws, size_t ws_size,
                              hipStream_t stream)
{
    const float* x1  = (const float*)d_in[0];
    const float* x2  = (const float*)d_in[1];
    const float* w1  = (const float*)d_in[2];
    const float* w2  = (const float*)d_in[3];
    const float* thr = (const float*)d_in[4];

    int* sel = (int*)d_ws;   // 512 ints = 2 KiB of scratch

    setup_sel_kernel<<<1, C_CH, 0, stream>>>(w1, w2, thr, sel);

    gather_planes_kernel<<<2 * B_N * C_CH, 832, 0, stream>>>(
        (const v4f*)x1, (const v4f*)x2, sel, (v4f*)d_out);
}